// Round 14
// baseline (307.731 us; speedup 1.0000x reference)
//
#include <hip/hip_runtime.h>
#include <math.h>

// Chamfer loss, B=32, N=2048, 3 used components.
// R14 = R13 (16x16x32 MFMA, full bf16-split, absmax 0.0) with ALL cross-lane
// work hoisted out of the main loop. Evidence: R8(scalar)/R10(32x32)/
// R13(16x16) all land at 79-80us total => main kernel ~26us regardless of
// instruction count => bound by the per-iteration serial shfl+shfl+LDS-atomic
// chain (un-hideable cross-lane latency at 4-6 waves/SIMD), not by issue.
// Fix: per-lane col-min of tile t goes to a STATICALLY-INDEXED 32-reg array
// colL[t] (full unroll); loop body = ds_read(prefetched) + 2 MFMA + 8 indep
// fmin + 4-op tree. The 32x(2 shfl + LDS atomicMin) runs ONCE in epilogue.
// Slot map, staging, partials, sum kernel: identical to R13 (passed).
//   g0: A=[phx,phy,phz, plx,ply,plz, x2h,x2l] B=[ghx,ghy,ghz, glx,gly,glz, 1,1]
//   g1: A=[phx,phy,phz, 1,1, 0,0,0]           B=[glx,gly,glz, y2h,y2l, 0,0,0]
//   g2: A=[plx,ply,plz, 0..]                  B=[ghx,ghy,ghz, 0..]
//   g3: A=0
// C/D layout (m89/m91): col=lane&15, row=(lane>>4)*4+reg.
// Block = 128 rows x 512 cols, grid (16,4,32)=2048; 2 dispatches, no memsets.

#define NPTS   2048
#define NBATCH 32
#define BROWS  128
#define BCOLS  512
#define NBI    (NPTS / BROWS)          // 16
#define NJC    (NPTS / BCOLS)          // 4
#define WS_ROW_FLOATS ((size_t)NBATCH * NBI * NJC * BROWS)   // 262144 floats
#define EPSF   1e-16f
#define BIGF   3.4e38f
#define ONEBF  0x3F80u                 // bf16 1.0

typedef __attribute__((ext_vector_type(8))) short bf16x8;
typedef __attribute__((ext_vector_type(4))) float f32x4;
typedef __attribute__((ext_vector_type(4))) unsigned int u32x4;

__device__ __forceinline__ float min3f(float a, float b, float c) {
    return fminf(fminf(a, b), c);      // -> v_min3_f32
}
__device__ __forceinline__ unsigned short bf16_rne(float f) {
    unsigned int u = __float_as_uint(f);
    return (unsigned short)((u + 0x7FFFu + ((u >> 16) & 1u)) >> 16);
}
__device__ __forceinline__ float bf16_f32(unsigned short h) {
    return __uint_as_float(((unsigned int)h) << 16);
}

__global__ __launch_bounds__(256, 4) void chamfer_mfma_kernel(
    const float* __restrict__ P, const float* __restrict__ Q,
    float* __restrict__ ws, float* __restrict__ out)
{
    __shared__ u32x4        sB0[BCOLS];   // B-frag group0 (8 KB)
    __shared__ u32x4        sB1[BCOLS];   // B-frag group1 (8 KB)
    __shared__ u32x4        sB2[BCOLS];   // B-frag group2 (8 KB)
    __shared__ unsigned int scol[BCOLS];  // col-min, uint-cast (2 KB)
    __shared__ float        srow[BROWS];  // row-min funnel (0.5 KB)

    const int tid  = threadIdx.x;
    const int lane = tid & 63;
    const int wv   = tid >> 6;
    const int c15  = lane & 15;        // col-in-tile / row-in-tile
    const int g    = lane >> 4;        // k slot-group 0..3
    const int bi   = blockIdx.x;       // 128-row chunk
    const int jc   = blockIdx.y;       // 512-col chunk
    const int b    = blockIdx.z;       // batch

    if (bi == 0 && jc == 0 && b == 0 && tid == 0) *out = 0.f;

    // ---- stage B frags: 2 cols/thread
    {
        const float4* Qb = (const float4*)Q + (size_t)b * NPTS + jc * BCOLS;
        #pragma unroll
        for (int s = 0; s < 2; ++s) {
            int c = tid + 256 * s;
            float4 qv = Qb[c];
            float gx = -2.f * qv.y, gy = -2.f * qv.z, gz = -2.f * qv.w;
            unsigned short hx = bf16_rne(gx), hy = bf16_rne(gy), hz = bf16_rne(gz);
            unsigned short lx = bf16_rne(gx - bf16_f32(hx));
            unsigned short ly = bf16_rne(gy - bf16_f32(hy));
            unsigned short lz = bf16_rne(gz - bf16_f32(hz));
            float y2 = fmaf(qv.y, qv.y, fmaf(qv.z, qv.z, qv.w * qv.w));
            unsigned short y2h = bf16_rne(y2);
            unsigned short y2l = bf16_rne(y2 - bf16_f32(y2h));
            sB0[c] = (u32x4){ (unsigned)hx | ((unsigned)hy << 16),
                              (unsigned)hz | ((unsigned)lx << 16),
                              (unsigned)ly | ((unsigned)lz << 16),
                              ONEBF | (ONEBF << 16) };
            sB1[c] = (u32x4){ (unsigned)lx | ((unsigned)ly << 16),
                              (unsigned)lz | ((unsigned)y2h << 16),
                              (unsigned)y2l, 0u };
            sB2[c] = (u32x4){ (unsigned)hx | ((unsigned)hy << 16),
                              (unsigned)hz, 0u, 0u };
            scol[c] = 0x7F7F7F7Fu;
        }
    }

    // ---- A frags for my 2 rows (MFMA0: wave rows 0-15, MFMA1: 16-31)
    bf16x8 afrag0, afrag1;
    {
        const float4* Pb = (const float4*)P + (size_t)b * NPTS
                         + bi * BROWS + wv * 32;
        #pragma unroll
        for (int h = 0; h < 2; ++h) {
            float4 pv = Pb[h * 16 + c15];
            float x = pv.y, y = pv.z, z = pv.w;
            unsigned short hx = bf16_rne(x), hy = bf16_rne(y), hz = bf16_rne(z);
            unsigned short lx = bf16_rne(x - bf16_f32(hx));
            unsigned short ly = bf16_rne(y - bf16_f32(hy));
            unsigned short lz = bf16_rne(z - bf16_f32(hz));
            float x2 = fmaf(x, x, fmaf(y, y, z * z));
            unsigned short x2h = bf16_rne(x2);
            unsigned short x2l = bf16_rne(x2 - bf16_f32(x2h));
            u32x4 a;
            if (g == 0)
                a = (u32x4){ (unsigned)hx | ((unsigned)hy << 16),
                             (unsigned)hz | ((unsigned)lx << 16),
                             (unsigned)ly | ((unsigned)lz << 16),
                             (unsigned)x2h | ((unsigned)x2l << 16) };
            else if (g == 1)
                a = (u32x4){ (unsigned)hx | ((unsigned)hy << 16),
                             (unsigned)hz | (ONEBF << 16),
                             ONEBF, 0u };
            else if (g == 2)
                a = (u32x4){ (unsigned)lx | ((unsigned)ly << 16),
                             (unsigned)lz, 0u, 0u };
            else
                a = (u32x4){ 0u, 0u, 0u, 0u };
            if (h == 0) afrag0 = __builtin_bit_cast(bf16x8, a);
            else        afrag1 = __builtin_bit_cast(bf16x8, a);
        }
    }
    __syncthreads();

    // ---- main loop: 32 col-tiles; NO cross-lane ops inside.
    const u32x4* bbase = (g == 0) ? sB0 : (g == 1) ? sB1 : sB2;  // g3: A=0
    const f32x4 cz = {0.f, 0.f, 0.f, 0.f};
    float ra0[4], ra1[4];
    #pragma unroll
    for (int r = 0; r < 4; ++r) { ra0[r] = BIGF; ra1[r] = BIGF; }
    float colL[32];                    // statically indexed (full unroll)

    bf16x8 bcur = __builtin_bit_cast(bf16x8, bbase[c15]);
    #pragma unroll
    for (int t = 0; t < 32; ++t) {
        bf16x8 bnext;
        if (t < 31) bnext = __builtin_bit_cast(bf16x8, bbase[(t + 1) * 16 + c15]);
        f32x4 d0 = __builtin_amdgcn_mfma_f32_16x16x32_bf16(afrag0, bcur, cz, 0, 0, 0);
        f32x4 d1 = __builtin_amdgcn_mfma_f32_16x16x32_bf16(afrag1, bcur, cz, 0, 0, 0);
        #pragma unroll
        for (int r = 0; r < 4; ++r) {
            ra0[r] = fminf(ra0[r], d0[r]);
            ra1[r] = fminf(ra1[r], d1[r]);
        }
        // per-lane col-min over my 8 rows of col t*16+c15 (stays in a reg)
        colL[t] = min3f(min3f(d0[0], d0[1], d0[2]),
                        min3f(d0[3], d1[0], d1[1]),
                        fminf(d1[2], d1[3]));
        bcur = bnext;
    }

    // ---- col epilogue (ONCE): merge g across lanes, publish via LDS atomic
    #pragma unroll
    for (int t = 0; t < 32; ++t) {
        float m = colL[t];
        m = fminf(m, __shfl_xor(m, 16));
        m = fminf(m, __shfl_xor(m, 32));
        if (lane < 16)
            atomicMin(&scol[t * 16 + lane], __float_as_uint(fmaxf(m, 0.f)));
    }

    // ---- row epilogue: min over cols = reduce across c15 bits
    #pragma unroll
    for (int r = 0; r < 4; ++r) {
        float v0 = ra0[r], v1 = ra1[r];
        v0 = fminf(v0, __shfl_xor(v0, 1)); v1 = fminf(v1, __shfl_xor(v1, 1));
        v0 = fminf(v0, __shfl_xor(v0, 2)); v1 = fminf(v1, __shfl_xor(v1, 2));
        v0 = fminf(v0, __shfl_xor(v0, 4)); v1 = fminf(v1, __shfl_xor(v1, 4));
        v0 = fminf(v0, __shfl_xor(v0, 8)); v1 = fminf(v1, __shfl_xor(v1, 8));
        if (c15 == 0) {                    // lanes 0,16,32,48: row g*4+r
            srow[wv * 32 + g * 4 + r]      = v0;
            srow[wv * 32 + 16 + g * 4 + r] = v1;
        }
    }
    __syncthreads();

    // ---- single-writer global partials (coalesced)
    if (tid < BROWS)
        ws[(((size_t)b * NBI + bi) * NJC + jc) * BROWS + tid] = srow[tid];
    {
        float* cb = ws + WS_ROW_FLOATS
                  + (((size_t)b * NJC + jc) * NBI + bi) * BCOLS;
        #pragma unroll
        for (int s = 0; s < 2; ++s) {
            int c = tid + 256 * s;
            cb[c] = __uint_as_float(scol[c]);   // clamped >= 0 already
        }
    }
}

__global__ __launch_bounds__(256) void chamfer_sum_kernel(
    const float* __restrict__ ws, float* __restrict__ out)
{
    __shared__ float rbuf[4];
    const int tid = threadIdx.x;
    const int i   = blockIdx.x * 256 + tid;   // 0..65535
    const int b   = i >> 11;
    const int e   = i & 2047;

    // row side: min over 4 jc partials
    float s;
    {
        const int bi = e >> 7, rl = e & 127;
        const float* rb = ws + ((size_t)(b * NBI + bi) * NJC) * BROWS + rl;
        float v = fminf(fminf(rb[0], rb[BROWS]),
                        fminf(rb[2 * BROWS], rb[3 * BROWS]));
        s = sqrtf(fmaxf(v, 0.f) + EPSF);
    }
    // col side: min over 16 bi partials (coalesced in cl)
    {
        const int jcx = e >> 9, cl = e & 511;
        const float* cb = ws + WS_ROW_FLOATS
                        + ((size_t)(b * NJC + jcx) * NBI) * BCOLS + cl;
        float v = BIGF;
        #pragma unroll
        for (int j = 0; j < NBI; ++j) v = fminf(v, cb[(size_t)j * BCOLS]);
        s += sqrtf(fmaxf(v, 0.f) + EPSF);
    }

    #pragma unroll
    for (int off = 32; off > 0; off >>= 1) s += __shfl_down(s, off);
    if ((tid & 63) == 0) rbuf[tid >> 6] = s;
    __syncthreads();
    if (tid == 0)
        atomicAdd(out, 0.5f * ((rbuf[0] + rbuf[1]) + (rbuf[2] + rbuf[3])));
}

extern "C" void kernel_launch(void* const* d_in, const int* in_sizes, int n_in,
                              void* d_out, int out_size, void* d_ws, size_t ws_size,
                              hipStream_t stream) {
    const float* P = (const float*)d_in[0];   // p[0] = first 32*2048*4 floats
    const float* Q = (const float*)d_in[1];
    float* out = (float*)d_out;
    float* ws  = (float*)d_ws;                // uses ~5.2 MiB

    dim3 grid(NBI, NJC, NBATCH);              // 16 x 4 x 32 = 2048 blocks
    chamfer_mfma_kernel<<<grid, 256, 0, stream>>>(P, Q, ws, out);
    chamfer_sum_kernel<<<256, 256, 0, stream>>>(ws, out);
}

// Round 15
// 110.581 us; speedup vs baseline: 2.7829x; 2.7829x over previous
//
#include <hip/hip_runtime.h>
#include <math.h>

// Chamfer loss, B=32, N=2048, 3 used components.
// R15 = R14's cross-lane hoist with SPILL-SAFE sizing (R14 diagnosed as pure
// scratch spill: FETCH 758MB, VGPR=64). Block = 128 rows x 256 cols -> only
// 16 col-tiles: colL[16] (16 VGPR, statically indexed under full unroll),
// no manual prefetch. Loop body = ds_read_b128 + 2 MFMA + 8 fmin + 7-op tree
// + 1 move; ZERO cross-lane ops. The 16x(2 shfl + LDS atomicMin) runs once
// in the epilogue. ~70-100 live VGPR < 128 cap, LDS 14KB, 4 blocks/CU.
// Slot map / bf16-split / partials / sum structure = R13 (passed, absmax 0):
//   g0: A=[phx,phy,phz, plx,ply,plz, x2h,x2l] B=[ghx,ghy,ghz, glx,gly,glz, 1,1]
//   g1: A=[phx,phy,phz, 1,1, 0,0,0]           B=[glx,gly,glz, y2h,y2l, 0,0,0]
//   g2: A=[plx,ply,plz, 0..]                  B=[ghx,ghy,ghz, 0..]
//   g3: A=0
// C/D layout (m89/m91): col=lane&15, row=(lane>>4)*4+reg.
// Grid (16,8,32)=4096 blocks; ws_row[b][bi][jc][128] 2MB + ws_col[b][jc][bi][256]
// 2MB, exact single-writer (no init). 2 dispatches, zero memsets.

#define NPTS   2048
#define NBATCH 32
#define BROWS  128
#define BCOLS  256
#define NBI    (NPTS / BROWS)          // 16
#define NJC    (NPTS / BCOLS)          // 8
#define NTILE  (BCOLS / 16)            // 16
#define WS_ROW_FLOATS ((size_t)NBATCH * NBI * NJC * BROWS)   // 524288 floats
#define EPSF   1e-16f
#define BIGF   3.4e38f
#define ONEBF  0x3F80u                 // bf16 1.0

typedef __attribute__((ext_vector_type(8))) short bf16x8;
typedef __attribute__((ext_vector_type(4))) float f32x4;
typedef __attribute__((ext_vector_type(4))) unsigned int u32x4;

__device__ __forceinline__ float min3f(float a, float b, float c) {
    return fminf(fminf(a, b), c);      // -> v_min3_f32
}
__device__ __forceinline__ unsigned short bf16_rne(float f) {
    unsigned int u = __float_as_uint(f);
    return (unsigned short)((u + 0x7FFFu + ((u >> 16) & 1u)) >> 16);
}
__device__ __forceinline__ float bf16_f32(unsigned short h) {
    return __uint_as_float(((unsigned int)h) << 16);
}

__global__ __launch_bounds__(256, 4) void chamfer_mfma_kernel(
    const float* __restrict__ P, const float* __restrict__ Q,
    float* __restrict__ ws, float* __restrict__ out)
{
    __shared__ u32x4        sB0[BCOLS];   // B-frag group0 (4 KB)
    __shared__ u32x4        sB1[BCOLS];   // B-frag group1 (4 KB)
    __shared__ u32x4        sB2[BCOLS];   // B-frag group2 (4 KB)
    __shared__ unsigned int scol[BCOLS];  // col-min, uint-cast (1 KB)
    __shared__ float        srow[BROWS];  // row-min funnel (0.5 KB)

    const int tid  = threadIdx.x;
    const int lane = tid & 63;
    const int wv   = tid >> 6;
    const int c15  = lane & 15;        // col-in-tile / row-in-tile
    const int g    = lane >> 4;        // k slot-group 0..3
    const int bi   = blockIdx.x;       // 128-row chunk
    const int jc   = blockIdx.y;       // 256-col chunk
    const int b    = blockIdx.z;       // batch

    if (bi == 0 && jc == 0 && b == 0 && tid == 0) *out = 0.f;

    // ---- stage B frags: 1 col/thread
    {
        const float4* Qb = (const float4*)Q + (size_t)b * NPTS + jc * BCOLS;
        int c = tid;
        float4 qv = Qb[c];
        float gx = -2.f * qv.y, gy = -2.f * qv.z, gz = -2.f * qv.w;
        unsigned short hx = bf16_rne(gx), hy = bf16_rne(gy), hz = bf16_rne(gz);
        unsigned short lx = bf16_rne(gx - bf16_f32(hx));
        unsigned short ly = bf16_rne(gy - bf16_f32(hy));
        unsigned short lz = bf16_rne(gz - bf16_f32(hz));
        float y2 = fmaf(qv.y, qv.y, fmaf(qv.z, qv.z, qv.w * qv.w));
        unsigned short y2h = bf16_rne(y2);
        unsigned short y2l = bf16_rne(y2 - bf16_f32(y2h));
        sB0[c] = (u32x4){ (unsigned)hx | ((unsigned)hy << 16),
                          (unsigned)hz | ((unsigned)lx << 16),
                          (unsigned)ly | ((unsigned)lz << 16),
                          ONEBF | (ONEBF << 16) };
        sB1[c] = (u32x4){ (unsigned)lx | ((unsigned)ly << 16),
                          (unsigned)lz | ((unsigned)y2h << 16),
                          (unsigned)y2l, 0u };
        sB2[c] = (u32x4){ (unsigned)hx | ((unsigned)hy << 16),
                          (unsigned)hz, 0u, 0u };
        scol[c] = 0x7F7F7F7Fu;
    }

    // ---- A frags for my 2 rows (MFMA0: wave rows 0-15, MFMA1: 16-31)
    bf16x8 afrag0, afrag1;
    {
        const float4* Pb = (const float4*)P + (size_t)b * NPTS
                         + bi * BROWS + wv * 32;
        #pragma unroll
        for (int h = 0; h < 2; ++h) {
            float4 pv = Pb[h * 16 + c15];
            float x = pv.y, y = pv.z, z = pv.w;
            unsigned short hx = bf16_rne(x), hy = bf16_rne(y), hz = bf16_rne(z);
            unsigned short lx = bf16_rne(x - bf16_f32(hx));
            unsigned short ly = bf16_rne(y - bf16_f32(hy));
            unsigned short lz = bf16_rne(z - bf16_f32(hz));
            float x2 = fmaf(x, x, fmaf(y, y, z * z));
            unsigned short x2h = bf16_rne(x2);
            unsigned short x2l = bf16_rne(x2 - bf16_f32(x2h));
            u32x4 a;
            if (g == 0)
                a = (u32x4){ (unsigned)hx | ((unsigned)hy << 16),
                             (unsigned)hz | ((unsigned)lx << 16),
                             (unsigned)ly | ((unsigned)lz << 16),
                             (unsigned)x2h | ((unsigned)x2l << 16) };
            else if (g == 1)
                a = (u32x4){ (unsigned)hx | ((unsigned)hy << 16),
                             (unsigned)hz | (ONEBF << 16),
                             ONEBF, 0u };
            else if (g == 2)
                a = (u32x4){ (unsigned)lx | ((unsigned)ly << 16),
                             (unsigned)lz, 0u, 0u };
            else
                a = (u32x4){ 0u, 0u, 0u, 0u };
            if (h == 0) afrag0 = __builtin_bit_cast(bf16x8, a);
            else        afrag1 = __builtin_bit_cast(bf16x8, a);
        }
    }
    __syncthreads();

    // ---- main loop: 16 col-tiles; NO cross-lane ops inside.
    const u32x4* bbase = (g == 0) ? sB0 : (g == 1) ? sB1 : sB2;  // g3: A=0
    const f32x4 cz = {0.f, 0.f, 0.f, 0.f};
    float ra0[4], ra1[4];
    #pragma unroll
    for (int r = 0; r < 4; ++r) { ra0[r] = BIGF; ra1[r] = BIGF; }
    float colL[NTILE];                 // statically indexed (full unroll)

    #pragma unroll
    for (int t = 0; t < NTILE; ++t) {
        bf16x8 bfrag = __builtin_bit_cast(bf16x8, bbase[t * 16 + c15]);
        f32x4 d0 = __builtin_amdgcn_mfma_f32_16x16x32_bf16(afrag0, bfrag, cz, 0, 0, 0);
        f32x4 d1 = __builtin_amdgcn_mfma_f32_16x16x32_bf16(afrag1, bfrag, cz, 0, 0, 0);
        #pragma unroll
        for (int r = 0; r < 4; ++r) {
            ra0[r] = fminf(ra0[r], d0[r]);
            ra1[r] = fminf(ra1[r], d1[r]);
        }
        colL[t] = min3f(min3f(d0[0], d0[1], d0[2]),
                        min3f(d0[3], d1[0], d1[1]),
                        fminf(d1[2], d1[3]));
    }

    // ---- col epilogue (ONCE): merge g across lanes, publish via LDS atomic
    #pragma unroll
    for (int t = 0; t < NTILE; ++t) {
        float m = colL[t];
        m = fminf(m, __shfl_xor(m, 16));
        m = fminf(m, __shfl_xor(m, 32));
        if (lane < 16)
            atomicMin(&scol[t * 16 + lane], __float_as_uint(fmaxf(m, 0.f)));
    }

    // ---- row epilogue: min over cols = reduce across c15 bits
    #pragma unroll
    for (int r = 0; r < 4; ++r) {
        float v0 = ra0[r], v1 = ra1[r];
        v0 = fminf(v0, __shfl_xor(v0, 1)); v1 = fminf(v1, __shfl_xor(v1, 1));
        v0 = fminf(v0, __shfl_xor(v0, 2)); v1 = fminf(v1, __shfl_xor(v1, 2));
        v0 = fminf(v0, __shfl_xor(v0, 4)); v1 = fminf(v1, __shfl_xor(v1, 4));
        v0 = fminf(v0, __shfl_xor(v0, 8)); v1 = fminf(v1, __shfl_xor(v1, 8));
        if (c15 == 0) {                    // lanes 0,16,32,48: row g*4+r
            srow[wv * 32 + g * 4 + r]      = v0;
            srow[wv * 32 + 16 + g * 4 + r] = v1;
        }
    }
    __syncthreads();

    // ---- single-writer global partials (coalesced)
    if (tid < BROWS)
        ws[(((size_t)b * NBI + bi) * NJC + jc) * BROWS + tid] = srow[tid];
    {
        float* cb = ws + WS_ROW_FLOATS
                  + (((size_t)b * NJC + jc) * NBI + bi) * BCOLS;
        cb[tid] = __uint_as_float(scol[tid]);   // clamped >= 0 already
    }
}

__global__ __launch_bounds__(256) void chamfer_sum_kernel(
    const float* __restrict__ ws, float* __restrict__ out)
{
    __shared__ float rbuf[4];
    const int tid = threadIdx.x;
    const int i   = blockIdx.x * 256 + tid;   // 0..65535
    const int b   = i >> 11;
    const int e   = i & 2047;

    // row side: min over 8 jc partials (coalesced in rl)
    float s;
    {
        const int bi = e >> 7, rl = e & 127;
        const float* rb = ws + ((size_t)(b * NBI + bi) * NJC) * BROWS + rl;
        float v = BIGF;
        #pragma unroll
        for (int j = 0; j < NJC; ++j) v = fminf(v, rb[(size_t)j * BROWS]);
        s = sqrtf(fmaxf(v, 0.f) + EPSF);
    }
    // col side: min over 16 bi partials (coalesced in cl)
    {
        const int jcx = e >> 8, cl = e & 255;
        const float* cb = ws + WS_ROW_FLOATS
                        + ((size_t)(b * NJC + jcx) * NBI) * BCOLS + cl;
        float v = BIGF;
        #pragma unroll
        for (int j = 0; j < NBI; ++j) v = fminf(v, cb[(size_t)j * BCOLS]);
        s += sqrtf(fmaxf(v, 0.f) + EPSF);
    }

    #pragma unroll
    for (int off = 32; off > 0; off >>= 1) s += __shfl_down(s, off);
    if ((tid & 63) == 0) rbuf[tid >> 6] = s;
    __syncthreads();
    if (tid == 0)
        atomicAdd(out, 0.5f * ((rbuf[0] + rbuf[1]) + (rbuf[2] + rbuf[3])));
}

extern "C" void kernel_launch(void* const* d_in, const int* in_sizes, int n_in,
                              void* d_out, int out_size, void* d_ws, size_t ws_size,
                              hipStream_t stream) {
    const float* P = (const float*)d_in[0];   // p[0] = first 32*2048*4 floats
    const float* Q = (const float*)d_in[1];
    float* out = (float*)d_out;
    float* ws  = (float*)d_ws;                // uses 4 MiB

    dim3 grid(NBI, NJC, NBATCH);              // 16 x 8 x 32 = 4096 blocks
    chamfer_mfma_kernel<<<grid, 256, 0, stream>>>(P, Q, ws, out);
    chamfer_sum_kernel<<<256, 256, 0, stream>>>(ws, out);
}

// Round 16
// 97.597 us; speedup vs baseline: 3.1531x; 1.1330x over previous
//
#include <hip/hip_runtime.h>
#include <math.h>

// Chamfer loss, B=32, N=2048, 3 used components.
// R16 = R15 with ONE change: __launch_bounds__(256) (no min-occupancy arg).
// Diagnosis chain: every MFMA variant carried __launch_bounds__(256,4) and
// every one visible in counters reports VGPR_Count=64 + scratch traffic
// (R14: 758MB FETCH; R15: 80MB WRITE = ~18 spilled floats/thread). Scalar
// kernels without the min-arg got VGPR=100, no scratch. The occupancy pin
// makes the compiler split the unified file (64 arch VGPR + AGPRs) and
// spill. Dropping the pin raises the cap to 256 arch VGPRs; expected alloc
// ~100-130 -> same 4-waves/SIMD occupancy, ZERO spill.
// Everything else byte-identical to R15 (clean A/B):
// Block = 128 rows x 256 cols, 16 col-tiles; colL[16] statically indexed;
// loop body = ds_read_b128 + 2 MFMA + 8 fmin + 7-op tree, zero cross-lane;
// 16x(2 shfl + LDS atomicMin) once in epilogue.
// Slot map / bf16-split (full 4-product) / partials / sum = R13 (passed):
//   g0: A=[phx,phy,phz, plx,ply,plz, x2h,x2l] B=[ghx,ghy,ghz, glx,gly,glz, 1,1]
//   g1: A=[phx,phy,phz, 1,1, 0,0,0]           B=[glx,gly,glz, y2h,y2l, 0,0,0]
//   g2: A=[plx,ply,plz, 0..]                  B=[ghx,ghy,ghz, 0..]
//   g3: A=0
// C/D layout (m89/m91): col=lane&15, row=(lane>>4)*4+reg.
// Grid (16,8,32)=4096; ws_row 2MB + ws_col 2MB single-writer (no init).
// 2 dispatches, zero memsets.

#define NPTS   2048
#define NBATCH 32
#define BROWS  128
#define BCOLS  256
#define NBI    (NPTS / BROWS)          // 16
#define NJC    (NPTS / BCOLS)          // 8
#define NTILE  (BCOLS / 16)            // 16
#define WS_ROW_FLOATS ((size_t)NBATCH * NBI * NJC * BROWS)   // 524288 floats
#define EPSF   1e-16f
#define BIGF   3.4e38f
#define ONEBF  0x3F80u                 // bf16 1.0

typedef __attribute__((ext_vector_type(8))) short bf16x8;
typedef __attribute__((ext_vector_type(4))) float f32x4;
typedef __attribute__((ext_vector_type(4))) unsigned int u32x4;

__device__ __forceinline__ float min3f(float a, float b, float c) {
    return fminf(fminf(a, b), c);      // -> v_min3_f32
}
__device__ __forceinline__ unsigned short bf16_rne(float f) {
    unsigned int u = __float_as_uint(f);
    return (unsigned short)((u + 0x7FFFu + ((u >> 16) & 1u)) >> 16);
}
__device__ __forceinline__ float bf16_f32(unsigned short h) {
    return __uint_as_float(((unsigned int)h) << 16);
}

__global__ __launch_bounds__(256) void chamfer_mfma_kernel(
    const float* __restrict__ P, const float* __restrict__ Q,
    float* __restrict__ ws, float* __restrict__ out)
{
    __shared__ u32x4        sB0[BCOLS];   // B-frag group0 (4 KB)
    __shared__ u32x4        sB1[BCOLS];   // B-frag group1 (4 KB)
    __shared__ u32x4        sB2[BCOLS];   // B-frag group2 (4 KB)
    __shared__ unsigned int scol[BCOLS];  // col-min, uint-cast (1 KB)
    __shared__ float        srow[BROWS];  // row-min funnel (0.5 KB)

    const int tid  = threadIdx.x;
    const int lane = tid & 63;
    const int wv   = tid >> 6;
    const int c15  = lane & 15;        // col-in-tile / row-in-tile
    const int g    = lane >> 4;        // k slot-group 0..3
    const int bi   = blockIdx.x;       // 128-row chunk
    const int jc   = blockIdx.y;       // 256-col chunk
    const int b    = blockIdx.z;       // batch

    if (bi == 0 && jc == 0 && b == 0 && tid == 0) *out = 0.f;

    // ---- stage B frags: 1 col/thread
    {
        const float4* Qb = (const float4*)Q + (size_t)b * NPTS + jc * BCOLS;
        int c = tid;
        float4 qv = Qb[c];
        float gx = -2.f * qv.y, gy = -2.f * qv.z, gz = -2.f * qv.w;
        unsigned short hx = bf16_rne(gx), hy = bf16_rne(gy), hz = bf16_rne(gz);
        unsigned short lx = bf16_rne(gx - bf16_f32(hx));
        unsigned short ly = bf16_rne(gy - bf16_f32(hy));
        unsigned short lz = bf16_rne(gz - bf16_f32(hz));
        float y2 = fmaf(qv.y, qv.y, fmaf(qv.z, qv.z, qv.w * qv.w));
        unsigned short y2h = bf16_rne(y2);
        unsigned short y2l = bf16_rne(y2 - bf16_f32(y2h));
        sB0[c] = (u32x4){ (unsigned)hx | ((unsigned)hy << 16),
                          (unsigned)hz | ((unsigned)lx << 16),
                          (unsigned)ly | ((unsigned)lz << 16),
                          ONEBF | (ONEBF << 16) };
        sB1[c] = (u32x4){ (unsigned)lx | ((unsigned)ly << 16),
                          (unsigned)lz | ((unsigned)y2h << 16),
                          (unsigned)y2l, 0u };
        sB2[c] = (u32x4){ (unsigned)hx | ((unsigned)hy << 16),
                          (unsigned)hz, 0u, 0u };
        scol[c] = 0x7F7F7F7Fu;
    }

    // ---- A frags for my 2 rows (MFMA0: wave rows 0-15, MFMA1: 16-31)
    bf16x8 afrag0, afrag1;
    {
        const float4* Pb = (const float4*)P + (size_t)b * NPTS
                         + bi * BROWS + wv * 32;
        #pragma unroll
        for (int h = 0; h < 2; ++h) {
            float4 pv = Pb[h * 16 + c15];
            float x = pv.y, y = pv.z, z = pv.w;
            unsigned short hx = bf16_rne(x), hy = bf16_rne(y), hz = bf16_rne(z);
            unsigned short lx = bf16_rne(x - bf16_f32(hx));
            unsigned short ly = bf16_rne(y - bf16_f32(hy));
            unsigned short lz = bf16_rne(z - bf16_f32(hz));
            float x2 = fmaf(x, x, fmaf(y, y, z * z));
            unsigned short x2h = bf16_rne(x2);
            unsigned short x2l = bf16_rne(x2 - bf16_f32(x2h));
            u32x4 a;
            if (g == 0)
                a = (u32x4){ (unsigned)hx | ((unsigned)hy << 16),
                             (unsigned)hz | ((unsigned)lx << 16),
                             (unsigned)ly | ((unsigned)lz << 16),
                             (unsigned)x2h | ((unsigned)x2l << 16) };
            else if (g == 1)
                a = (u32x4){ (unsigned)hx | ((unsigned)hy << 16),
                             (unsigned)hz | (ONEBF << 16),
                             ONEBF, 0u };
            else if (g == 2)
                a = (u32x4){ (unsigned)lx | ((unsigned)ly << 16),
                             (unsigned)lz, 0u, 0u };
            else
                a = (u32x4){ 0u, 0u, 0u, 0u };
            if (h == 0) afrag0 = __builtin_bit_cast(bf16x8, a);
            else        afrag1 = __builtin_bit_cast(bf16x8, a);
        }
    }
    __syncthreads();

    // ---- main loop: 16 col-tiles; NO cross-lane ops inside.
    const u32x4* bbase = (g == 0) ? sB0 : (g == 1) ? sB1 : sB2;  // g3: A=0
    const f32x4 cz = {0.f, 0.f, 0.f, 0.f};
    float ra0[4], ra1[4];
    #pragma unroll
    for (int r = 0; r < 4; ++r) { ra0[r] = BIGF; ra1[r] = BIGF; }
    float colL[NTILE];                 // statically indexed (full unroll)

    #pragma unroll
    for (int t = 0; t < NTILE; ++t) {
        bf16x8 bfrag = __builtin_bit_cast(bf16x8, bbase[t * 16 + c15]);
        f32x4 d0 = __builtin_amdgcn_mfma_f32_16x16x32_bf16(afrag0, bfrag, cz, 0, 0, 0);
        f32x4 d1 = __builtin_amdgcn_mfma_f32_16x16x32_bf16(afrag1, bfrag, cz, 0, 0, 0);
        #pragma unroll
        for (int r = 0; r < 4; ++r) {
            ra0[r] = fminf(ra0[r], d0[r]);
            ra1[r] = fminf(ra1[r], d1[r]);
        }
        colL[t] = min3f(min3f(d0[0], d0[1], d0[2]),
                        min3f(d0[3], d1[0], d1[1]),
                        fminf(d1[2], d1[3]));
    }

    // ---- col epilogue (ONCE): merge g across lanes, publish via LDS atomic
    #pragma unroll
    for (int t = 0; t < NTILE; ++t) {
        float m = colL[t];
        m = fminf(m, __shfl_xor(m, 16));
        m = fminf(m, __shfl_xor(m, 32));
        if (lane < 16)
            atomicMin(&scol[t * 16 + lane], __float_as_uint(fmaxf(m, 0.f)));
    }

    // ---- row epilogue: min over cols = reduce across c15 bits
    #pragma unroll
    for (int r = 0; r < 4; ++r) {
        float v0 = ra0[r], v1 = ra1[r];
        v0 = fminf(v0, __shfl_xor(v0, 1)); v1 = fminf(v1, __shfl_xor(v1, 1));
        v0 = fminf(v0, __shfl_xor(v0, 2)); v1 = fminf(v1, __shfl_xor(v1, 2));
        v0 = fminf(v0, __shfl_xor(v0, 4)); v1 = fminf(v1, __shfl_xor(v1, 4));
        v0 = fminf(v0, __shfl_xor(v0, 8)); v1 = fminf(v1, __shfl_xor(v1, 8));
        if (c15 == 0) {                    // lanes 0,16,32,48: row g*4+r
            srow[wv * 32 + g * 4 + r]      = v0;
            srow[wv * 32 + 16 + g * 4 + r] = v1;
        }
    }
    __syncthreads();

    // ---- single-writer global partials (coalesced)
    if (tid < BROWS)
        ws[(((size_t)b * NBI + bi) * NJC + jc) * BROWS + tid] = srow[tid];
    {
        float* cb = ws + WS_ROW_FLOATS
                  + (((size_t)b * NJC + jc) * NBI + bi) * BCOLS;
        cb[tid] = __uint_as_float(scol[tid]);   // clamped >= 0 already
    }
}

__global__ __launch_bounds__(256) void chamfer_sum_kernel(
    const float* __restrict__ ws, float* __restrict__ out)
{
    __shared__ float rbuf[4];
    const int tid = threadIdx.x;
    const int i   = blockIdx.x * 256 + tid;   // 0..65535
    const int b   = i >> 11;
    const int e   = i & 2047;

    // row side: min over 8 jc partials (coalesced in rl)
    float s;
    {
        const int bi = e >> 7, rl = e & 127;
        const float* rb = ws + ((size_t)(b * NBI + bi) * NJC) * BROWS + rl;
        float v = BIGF;
        #pragma unroll
        for (int j = 0; j < NJC; ++j) v = fminf(v, rb[(size_t)j * BROWS]);
        s = sqrtf(fmaxf(v, 0.f) + EPSF);
    }
    // col side: min over 16 bi partials (coalesced in cl)
    {
        const int jcx = e >> 8, cl = e & 255;
        const float* cb = ws + WS_ROW_FLOATS
                        + ((size_t)(b * NJC + jcx) * NBI) * BCOLS + cl;
        float v = BIGF;
        #pragma unroll
        for (int j = 0; j < NBI; ++j) v = fminf(v, cb[(size_t)j * BCOLS]);
        s += sqrtf(fmaxf(v, 0.f) + EPSF);
    }

    #pragma unroll
    for (int off = 32; off > 0; off >>= 1) s += __shfl_down(s, off);
    if ((tid & 63) == 0) rbuf[tid >> 6] = s;
    __syncthreads();
    if (tid == 0)
        atomicAdd(out, 0.5f * ((rbuf[0] + rbuf[1]) + (rbuf[2] + rbuf[3])));
}

extern "C" void kernel_launch(void* const* d_in, const int* in_sizes, int n_in,
                              void* d_out, int out_size, void* d_ws, size_t ws_size,
                              hipStream_t stream) {
    const float* P = (const float*)d_in[0];   // p[0] = first 32*2048*4 floats
    const float* Q = (const float*)d_in[1];
    float* out = (float*)d_out;
    float* ws  = (float*)d_ws;                // uses 4 MiB

    dim3 grid(NBI, NJC, NBATCH);              // 16 x 8 x 32 = 4096 blocks
    chamfer_mfma_kernel<<<grid, 256, 0, stream>>>(P, Q, ws, out);
    chamfer_sum_kernel<<<256, 256, 0, stream>>>(ws, out);
}